// Round 2
// baseline (192.325 us; speedup 1.0000x reference)
//
#include <hip/hip_runtime.h>

// MultiPropMLP on MI355X: N=1M samples, MLP 16->64->64->1, per-sample weight
// set k in [0,8) via idxs. Inputs/outputs are FP32 buffers (values bf16-rounded
// by the harness). Plan: counting-sort sample ids by k, then MFMA bf16 GEMM
// over 128-row same-k tiles. bf16 conversion of inputs is exact.

typedef __attribute__((ext_vector_type(8))) short bfrag;   // 8 bf16 (4 VGPRs)
typedef __attribute__((ext_vector_type(4))) float ffrag;   // 4 fp32 acc

#define WS_COUNTS   0      // int[8]
#define WS_BSTART   8      // int[8]  bucket starts
#define WS_TSTART   16     // int[9]  tile starts (prefix of ceil(cnt/128))
#define WS_BBASE    32     // int[256*8] per-block bases
#define IMG_OFF     16384  // byte offset of weight images
#define IMG_STRIDE  15360  // bytes per k image
#define IDS_OFF_B   139264 // byte offset of sorted ids (= 16384 + 8*15360)

__device__ __forceinline__ unsigned short bf16r(float f) {
    unsigned int u = __float_as_uint(f);
    u += 0x7fffu + ((u >> 16) & 1u);
    return (unsigned short)(u >> 16);
}
__device__ __forceinline__ unsigned int bf16pack2(float a, float b) {
    return (unsigned int)bf16r(a) | ((unsigned int)bf16r(b) << 16);
}

// ---------- K0: build per-k weight images (transposed, padded, bf16) ----------
// image layout (bytes): W0t[64][40] bf16 @0 (k-padded to 32, cols 32..39 pad)
//                       W1t[64][72] bf16 @5120 (cols 64..71 pad)
//                       b0 f32[64] @14336, b1 f32[64] @14592,
//                       W2 f32[64] @14848, b2 f32 @15104
__global__ void k_build_images(const float* __restrict__ W0, const float* __restrict__ b0,
                               const float* __restrict__ W1, const float* __restrict__ b1,
                               const float* __restrict__ W2, const float* __restrict__ b2,
                               unsigned char* __restrict__ wsB) {
    const int k = blockIdx.x, t = threadIdx.x;
    unsigned char* img = wsB + IMG_OFF + k * IMG_STRIDE;
    unsigned short* w0t = (unsigned short*)img;
    unsigned short* w1t = (unsigned short*)(img + 5120);
    float* f = (float*)(img + 14336);
    for (int e = t; e < 64 * 40; e += 256) {
        int n = e / 40, i = e % 40;
        w0t[e] = (i < 16) ? bf16r(W0[k * 1024 + i * 64 + n]) : (unsigned short)0;
    }
    for (int e = t; e < 64 * 72; e += 256) {
        int n = e / 72, i = e % 72;
        w1t[e] = (i < 64) ? bf16r(W1[k * 4096 + i * 64 + n]) : (unsigned short)0;
    }
    if (t < 64) f[t] = b0[k * 64 + t];
    else if (t < 128) f[t] = b1[k * 64 + (t - 64)];
    else if (t < 192) f[t] = W2[k * 64 + (t - 128)];
    else if (t == 192) f[192] = b2[k];
}

// ---------- K1: zero header ----------
__global__ void k_zero_hdr(int* wsI) {
    if (threadIdx.x < 64) wsI[threadIdx.x] = 0;
}

// ---------- K2: per-block histogram + global bases ----------
__global__ void k_hist(const int* __restrict__ idxs, int* __restrict__ wsI) {
    __shared__ int cnt[8];
    const int t = threadIdx.x, b = blockIdx.x, lane = t & 63;
    if (t < 8) cnt[t] = 0;
    __syncthreads();
    const int base = b * 4096;
    for (int it = 0; it < 16; ++it) {
        int k = idxs[base + it * 256 + t];
        #pragma unroll
        for (int kk = 0; kk < 8; ++kk) {
            unsigned long long m = __ballot(k == kk);
            if (lane == 0 && m) atomicAdd(&cnt[kk], (int)__popcll(m));
        }
    }
    __syncthreads();
    if (t < 8) wsI[WS_BBASE + b * 8 + t] = atomicAdd(&wsI[WS_COUNTS + t], cnt[t]);
}

// ---------- K3: tiny scan ----------
__global__ void k_scan(int* wsI) {
    if (threadIdx.x == 0) {
        int s = 0, tt = 0;
        for (int k = 0; k < 8; ++k) {
            int c = wsI[WS_COUNTS + k];
            wsI[WS_BSTART + k] = s; s += c;
            wsI[WS_TSTART + k] = tt; tt += (c + 127) >> 7;
        }
        wsI[WS_TSTART + 8] = tt;
    }
}

// ---------- K4: stable-ish scatter (atomic-free ranks within block) ----------
__global__ void k_scatter(const int* __restrict__ idxs, int* __restrict__ wsI) {
    __shared__ int running[8];
    __shared__ int wcnt[4][8];
    const int t = threadIdx.x, b = blockIdx.x, lane = t & 63, w = t >> 6;
    if (t < 8) running[t] = 0;
    __syncthreads();
    const int base = b * 4096;
    int* ids = wsI + (IDS_OFF_B / 4);
    for (int it = 0; it < 16; ++it) {
        int n = base + it * 256 + t;
        int k = idxs[n];
        unsigned long long mymask = 0;
        #pragma unroll
        for (int kk = 0; kk < 8; ++kk) {
            unsigned long long m = __ballot(k == kk);
            if (k == kk) mymask = m;
            if (lane == 0) wcnt[w][kk] = (int)__popcll(m);
        }
        __syncthreads();
        int pre = running[k];
        for (int w2 = 0; w2 < w; ++w2) pre += wcnt[w2][k];
        int lrank = (int)__popcll(mymask & ((1ull << lane) - 1ull));
        ids[wsI[WS_BSTART + k] + wsI[WS_BBASE + b * 8 + k] + pre + lrank] = n;
        __syncthreads();
        if (t < 8) running[t] += wcnt[0][t] + wcnt[1][t] + wcnt[2][t] + wcnt[3][t];
        __syncthreads();
    }
}

// ---------- K5: MFMA MLP over 128-row same-k tiles ----------
// block = 256 thr = 4 waves; wave w handles rows [w*32, w*32+32) (2 M-tiles).
// LDS: image 15360 | X[128][40]bf16 10240 | H[128][72]bf16 18432 | ids 512
__global__ void k_mlp(const float* __restrict__ xs, const unsigned char* __restrict__ wsB,
                      float* __restrict__ out) {
    __shared__ __align__(16) unsigned char smem[44544];
    const int* wsI = (const int*)wsB;
    const int tile = blockIdx.x;
    if (tile >= wsI[WS_TSTART + 8]) return;
    int k = 0;
    while (k < 7 && tile >= wsI[WS_TSTART + k + 1]) ++k;
    const int rowBase = (tile - wsI[WS_TSTART + k]) * 128;
    const int valid = min(128, wsI[WS_COUNTS + k] - rowBase);
    const int idsBase = wsI[WS_BSTART + k] + rowBase;

    const int tid = threadIdx.x;
    const int lane = tid & 63, w = tid >> 6, q = lane >> 4, l15 = lane & 15;

    unsigned short* Xs = (unsigned short*)(smem + 15360);
    unsigned short* Hs = (unsigned short*)(smem + 25600);
    int* idsLds = (int*)(smem + 44032);

    // stage ids + weight image
    const int* idsG = (const int*)(wsB + IDS_OFF_B);
    if (tid < 128) idsLds[tid] = idsG[idsBase + min(tid, valid - 1)];
    {
        const uint4* gimg = (const uint4*)(wsB + IMG_OFF + k * IMG_STRIDE);
        uint4* simg = (uint4*)smem;
        for (int e = tid; e < IMG_STRIDE / 16; e += 256) simg[e] = gimg[e];
    }
    __syncthreads();

    // gather X rows (fp32 -> bf16, zero-pad K 16..31)
    {
        const int r = tid >> 1, half = tid & 1;
        const int rid = idsLds[r];
        const float4* xp = (const float4*)(xs + (size_t)rid * 16 + half * 8);
        float4 v0 = xp[0], v1 = xp[1];
        uint4 pk;
        pk.x = bf16pack2(v0.x, v0.y);
        pk.y = bf16pack2(v0.z, v0.w);
        pk.z = bf16pack2(v1.x, v1.y);
        pk.w = bf16pack2(v1.z, v1.w);
        *(uint4*)(Xs + r * 40 + half * 8) = pk;
        uint4 z; z.x = z.y = z.z = z.w = 0;
        *(uint4*)(Xs + r * 40 + 16 + half * 8) = z;
    }
    __syncthreads();

    const unsigned short* W0t = (const unsigned short*)smem;
    const unsigned short* W1t = (const unsigned short*)(smem + 5120);
    const float* B0 = (const float*)(smem + 14336);
    const float* B1 = (const float*)(smem + 14592);
    const float* W2s = (const float*)(smem + 14848);
    const float b2v = *(const float*)(smem + 15104);

    // ---- layer 0: X[128x32] @ W0t -> H (relu, bf16) ----
    #pragma unroll
    for (int nt = 0; nt < 4; ++nt) {
        bfrag b = *(const bfrag*)(W0t + (nt * 16 + l15) * 40 + q * 8);
        float bv = B0[nt * 16 + l15];
        #pragma unroll
        for (int mt = 0; mt < 2; ++mt) {
            bfrag a = *(const bfrag*)(Xs + (w * 32 + mt * 16 + l15) * 40 + q * 8);
            ffrag acc = {0.f, 0.f, 0.f, 0.f};
            acc = __builtin_amdgcn_mfma_f32_16x16x32_bf16(a, b, acc, 0, 0, 0);
            #pragma unroll
            for (int r = 0; r < 4; ++r) {
                float h = fmaxf(acc[r] + bv, 0.f);
                Hs[(w * 32 + mt * 16 + q * 4 + r) * 72 + nt * 16 + l15] = bf16r(h);
            }
        }
    }
    __syncthreads();

    // ---- layer 1: H[128x64] @ W1t -> acc1 (in regs) ----
    ffrag acc1[2][4];
    #pragma unroll
    for (int mt = 0; mt < 2; ++mt)
        #pragma unroll
        for (int nt = 0; nt < 4; ++nt) { ffrag z = {0.f,0.f,0.f,0.f}; acc1[mt][nt] = z; }
    #pragma unroll
    for (int ks = 0; ks < 2; ++ks) {
        bfrag a0 = *(const bfrag*)(Hs + (w * 32 + 0  + l15) * 72 + ks * 32 + q * 8);
        bfrag a1 = *(const bfrag*)(Hs + (w * 32 + 16 + l15) * 72 + ks * 32 + q * 8);
        #pragma unroll
        for (int nt = 0; nt < 4; ++nt) {
            bfrag bb = *(const bfrag*)(W1t + (nt * 16 + l15) * 72 + ks * 32 + q * 8);
            acc1[0][nt] = __builtin_amdgcn_mfma_f32_16x16x32_bf16(a0, bb, acc1[0][nt], 0, 0, 0);
            acc1[1][nt] = __builtin_amdgcn_mfma_f32_16x16x32_bf16(a1, bb, acc1[1][nt], 0, 0, 0);
        }
    }

    // ---- layer 2: relu(acc1 + b1) . W2 + b2, reduce across n-lanes ----
    float bv1[4], wv[4];
    #pragma unroll
    for (int nt = 0; nt < 4; ++nt) {
        bv1[nt] = B1[nt * 16 + l15];
        wv[nt]  = W2s[nt * 16 + l15];
    }
    #pragma unroll
    for (int mt = 0; mt < 2; ++mt) {
        #pragma unroll
        for (int r = 0; r < 4; ++r) {
            float p = 0.f;
            #pragma unroll
            for (int nt = 0; nt < 4; ++nt) {
                float h = fmaxf(acc1[mt][nt][r] + bv1[nt], 0.f);
                p = fmaf(h, wv[nt], p);
            }
            p += __shfl_xor(p, 1);
            p += __shfl_xor(p, 2);
            p += __shfl_xor(p, 4);
            p += __shfl_xor(p, 8);
            int row = w * 32 + mt * 16 + q * 4 + r;
            if (l15 == 0 && row < valid) out[idsLds[row]] = p + b2v;
        }
    }
}

// ---------- fallback: per-thread fp32 (if ws too small / unexpected N) ----------
__global__ void k_fallback(const int* __restrict__ idxs, const float* __restrict__ xs,
                           const float* __restrict__ W0, const float* __restrict__ b0,
                           const float* __restrict__ W1, const float* __restrict__ b1,
                           const float* __restrict__ W2, const float* __restrict__ b2,
                           float* __restrict__ out, int N) {
    int n = blockIdx.x * blockDim.x + threadIdx.x;
    if (n >= N) return;
    int k = idxs[n];
    float h0[64];
    #pragma unroll
    for (int j = 0; j < 64; ++j) h0[j] = b0[k * 64 + j];
    for (int i = 0; i < 16; ++i) {
        float xi = xs[(size_t)n * 16 + i];
        #pragma unroll
        for (int j = 0; j < 64; ++j) h0[j] = fmaf(xi, W0[k * 1024 + i * 64 + j], h0[j]);
    }
    #pragma unroll
    for (int j = 0; j < 64; ++j) h0[j] = fmaxf(h0[j], 0.f);
    float acc = b2[k];
    for (int jc = 0; jc < 4; ++jc) {
        float h1[16];
        #pragma unroll
        for (int j = 0; j < 16; ++j) h1[j] = b1[k * 64 + jc * 16 + j];
        for (int i = 0; i < 64; ++i) {
            float hv = h0[i];
            #pragma unroll
            for (int j = 0; j < 16; ++j)
                h1[j] = fmaf(hv, W1[k * 4096 + i * 64 + jc * 16 + j], h1[j]);
        }
        #pragma unroll
        for (int j = 0; j < 16; ++j) acc = fmaf(fmaxf(h1[j], 0.f), W2[k * 64 + jc * 16 + j], acc);
    }
    out[n] = acc;
}

extern "C" void kernel_launch(void* const* d_in, const int* in_sizes, int n_in,
                              void* d_out, int out_size, void* d_ws, size_t ws_size,
                              hipStream_t stream) {
    const int*   idxs = (const int*)d_in[0];
    const float* xs   = (const float*)d_in[1];
    const float* W0   = (const float*)d_in[2];
    const float* b0   = (const float*)d_in[3];
    const float* W1   = (const float*)d_in[4];
    const float* b1   = (const float*)d_in[5];
    const float* W2   = (const float*)d_in[6];
    const float* b2   = (const float*)d_in[7];
    float* out = (float*)d_out;
    const int N = in_sizes[0];  // 1,048,576

    const size_t need = (size_t)IDS_OFF_B + (size_t)N * 4;
    if (N != 1048576 || ws_size < need) {
        k_fallback<<<(N + 255) / 256, 256, 0, stream>>>(idxs, xs, W0, b0, W1, b1, W2, b2, out, N);
        return;
    }

    unsigned char* wsB = (unsigned char*)d_ws;
    int* wsI = (int*)d_ws;
    k_build_images<<<8, 256, 0, stream>>>(W0, b0, W1, b1, W2, b2, wsB);
    k_zero_hdr<<<1, 64, 0, stream>>>(wsI);
    k_hist<<<256, 256, 0, stream>>>(idxs, wsI);
    k_scan<<<1, 64, 0, stream>>>(wsI);
    k_scatter<<<256, 256, 0, stream>>>(idxs, wsI);
    const int maxTiles = N / 128 + 8;  // 8200
    k_mlp<<<maxTiles, 256, 0, stream>>>(xs, wsB, out);
}

// Round 3
// 168.226 us; speedup vs baseline: 1.1433x; 1.1433x over previous
//
#include <hip/hip_runtime.h>

// MultiPropMLP on MI355X: N=1M samples, MLP 16->64->64->1, per-sample weight
// set k in [0,8) via idxs (fp32 buffers, bf16-rounded values).
// Round 3: block-local counting sort (1024-sample spans) so the MLP kernel's
// X gather stays inside a 64 KB L2-hot window; weights pre-swizzled to exact
// MFMA B-fragment layout and held in registers; 16-row subtiles per wave.

typedef __attribute__((ext_vector_type(8))) short bfrag;   // 8 bf16 (4 VGPRs)
typedef __attribute__((ext_vector_type(4))) float ffrag;   // 4 fp32 acc

#define SPAN        1024
#define NSPANS      1024
#define IMG_OFF     32768            // after counts int[1024*8]
#define IMG_STRIDE  13312            // W0B 4096 | W1B 8192 | bias 772 -> pad
#define GIDS_OFF    (IMG_OFF + 8 * IMG_STRIDE)   // = 139264

__device__ __forceinline__ unsigned short bf16r(float f) {
    unsigned int u = __float_as_uint(f);
    u += 0x7fffu + ((u >> 16) & 1u);
    return (unsigned short)(u >> 16);
}
__device__ __forceinline__ unsigned int bf16pack2(float a, float b) {
    return (unsigned int)bf16r(a) | ((unsigned int)bf16r(b) << 16);
}

// ---------- K0: build per-k weight images in MFMA B-fragment order ----------
// W0B bf16[4 nt][64 lane][8 j]  : element = W0[k][(lane>>4)*8+j][nt*16+(lane&15)], 0 for k-dim >= 16
// W1B bf16[4 nt][2 ks][64][8 j] : element = W1[k][ks*32+(lane>>4)*8+j][nt*16+(lane&15)]
// bias f32: b0[64] | b1[64] | W2[64] | b2
__global__ void k_build_images(const float* __restrict__ W0, const float* __restrict__ b0,
                               const float* __restrict__ W1, const float* __restrict__ b1,
                               const float* __restrict__ W2, const float* __restrict__ b2,
                               unsigned char* __restrict__ wsB) {
    const int k = blockIdx.x, t = threadIdx.x;
    unsigned char* img = wsB + IMG_OFF + k * IMG_STRIDE;
    unsigned short* w0b = (unsigned short*)img;
    unsigned short* w1b = (unsigned short*)(img + 4096);
    float* bias = (float*)(img + 12288);
    for (int e = t; e < 2048; e += 256) {
        int j = e & 7, lane = (e >> 3) & 63, nt = e >> 9;
        int kk = ((lane >> 4) * 8) + j;
        w0b[e] = (kk < 16) ? bf16r(W0[k * 1024 + kk * 64 + nt * 16 + (lane & 15)])
                           : (unsigned short)0;
    }
    for (int e = t; e < 4096; e += 256) {
        int j = e & 7, lane = (e >> 3) & 63, ks = (e >> 9) & 1, nt = e >> 10;
        int kk = ks * 32 + ((lane >> 4) * 8) + j;
        w1b[e] = bf16r(W1[k * 4096 + kk * 64 + nt * 16 + (lane & 15)]);
    }
    if (t < 64) bias[t] = b0[k * 64 + t];
    else if (t < 128) bias[64 + (t - 64)] = b1[k * 64 + (t - 64)];
    else if (t < 192) bias[128 + (t - 128)] = W2[k * 64 + (t - 128)];
    else if (t == 192) bias[192] = b2[k];
}

// ---------- K1: block-local counting sort over 1024-sample spans ----------
// Writes gids[span*1024 + r] = global sample id in (k-bucketed, stable) order,
// and counts[span*8 + k].
__global__ __launch_bounds__(256) void k_sort(const int* __restrict__ idxs,
                                              int* __restrict__ wsI) {
    __shared__ int wcnt[4][4][8];    // [iter][wave][k]
    __shared__ int bsbase[4][4][8];  // absolute scatter base
    __shared__ int cnt[8], start[8];
    __shared__ int sId[SPAN];
    const int tid = threadIdx.x, lane = tid & 63, w = tid >> 6;
    const int base = blockIdx.x * SPAN;

    int kreg[4], lrank[4];
    #pragma unroll
    for (int it = 0; it < 4; ++it) {
        int k = idxs[base + it * 256 + tid];
        kreg[it] = k;
        unsigned long long mymask = 0;
        #pragma unroll
        for (int kk = 0; kk < 8; ++kk) {
            unsigned long long m = __ballot(k == kk);
            if (k == kk) mymask = m;
            if (lane == 0) wcnt[it][w][kk] = (int)__popcll(m);
        }
        lrank[it] = (int)__popcll(mymask & ((1ull << lane) - 1ull));
    }
    __syncthreads();
    if (tid < 8) {
        int c = 0;
        for (int it = 0; it < 4; ++it)
            for (int w2 = 0; w2 < 4; ++w2) c += wcnt[it][w2][tid];
        cnt[tid] = c;
        wsI[blockIdx.x * 8 + tid] = c;
    }
    __syncthreads();
    if (tid == 0) {
        int s = 0;
        for (int k = 0; k < 8; ++k) { start[k] = s; s += cnt[k]; }
    }
    __syncthreads();
    if (tid < 128) {
        int it = tid >> 5, w2 = (tid >> 3) & 3, kk = tid & 7;
        int b = start[kk];
        for (int it2 = 0; it2 < it; ++it2)
            for (int w3 = 0; w3 < 4; ++w3) b += wcnt[it2][w3][kk];
        for (int w3 = 0; w3 < w2; ++w3) b += wcnt[it][w3][kk];
        bsbase[it][w2][kk] = b;
    }
    __syncthreads();
    #pragma unroll
    for (int it = 0; it < 4; ++it)
        sId[bsbase[it][w][kreg[it]] + lrank[it]] = it * 256 + tid;
    __syncthreads();
    int* gids = wsI + (GIDS_OFF / 4);
    for (int r = tid; r < SPAN; r += 256)
        gids[base + r] = base + sId[r];
}

// ---------- K2: fused MLP, one 1024-sample span per block ----------
__device__ __forceinline__ int load_a(const float* __restrict__ xs,
                                      const int* __restrict__ gidb,
                                      int stBase, int l15, int q, int cnt,
                                      bfrag* a) {
    int ridx = stBase + l15;
    ridx = ridx < cnt ? ridx : cnt - 1;
    int gid = gidb[ridx];
    bfrag av = {0, 0, 0, 0, 0, 0, 0, 0};
    if (q < 2) {
        const float4* xp = (const float4*)(xs + (size_t)gid * 16 + q * 8);
        float4 v0 = xp[0], v1 = xp[1];
        uint4 u;
        u.x = bf16pack2(v0.x, v0.y);
        u.y = bf16pack2(v0.z, v0.w);
        u.z = bf16pack2(v1.x, v1.y);
        u.w = bf16pack2(v1.z, v1.w);
        av = *(bfrag*)&u;
    }
    *a = av;
    return gid;
}

__global__ __launch_bounds__(256, 3) void k_mlp(const float* __restrict__ xs,
                                                const unsigned char* __restrict__ wsB,
                                                float* __restrict__ out) {
    __shared__ int gidb[SPAN];
    __shared__ unsigned short Hs[4][16 * 72];
    const int* counts = (const int*)wsB;
    const int* gidsG = (const int*)(wsB + GIDS_OFF);
    const int s = blockIdx.x;
    const int sbase = s * SPAN;
    const int tid = threadIdx.x, lane = tid & 63, w = tid >> 6;
    const int q = lane >> 4, l15 = lane & 15;
    unsigned short* H = Hs[w];

    int cs[9];
    cs[0] = 0;
    #pragma unroll
    for (int k = 0; k < 8; ++k) cs[k + 1] = cs[k] + counts[s * 8 + k];

    for (int k = 0; k < 8; ++k) {
        const int cnt = cs[k + 1] - cs[k];
        if (cnt == 0) continue;
        __syncthreads();  // gidb reuse guard (uniform branch: cs is block-uniform)
        for (int i = tid; i < cnt; i += 256) gidb[i] = gidsG[sbase + cs[k] + i];
        __syncthreads();

        const unsigned char* img = wsB + IMG_OFF + k * IMG_STRIDE;
        bfrag w0f[4], w1f[4][2];
        #pragma unroll
        for (int nt = 0; nt < 4; ++nt)
            w0f[nt] = *(const bfrag*)(img + nt * 1024 + lane * 16);
        #pragma unroll
        for (int nt = 0; nt < 4; ++nt)
            #pragma unroll
            for (int ks = 0; ks < 2; ++ks)
                w1f[nt][ks] = *(const bfrag*)(img + 4096 + ((nt * 2 + ks) * 64 + lane) * 16);
        const float* bias = (const float*)(img + 12288);
        float b0v[4], b1v[4], w2v[4];
        #pragma unroll
        for (int nt = 0; nt < 4; ++nt) {
            b0v[nt] = bias[nt * 16 + l15];
            b1v[nt] = bias[64 + nt * 16 + l15];
            w2v[nt] = bias[128 + nt * 16 + l15];
        }
        const float b2v = bias[192];

        const int nst = (cnt + 15) >> 4;
        int st = w;
        bfrag aCur;
        int gidCur = 0;
        if (st < nst) gidCur = load_a(xs, gidb, st * 16, l15, q, cnt, &aCur);

        while (st < nst) {
            // ---- layer 0: 16x16x32 with K zero-padded 16..31 ----
            ffrag acc0[4];
            #pragma unroll
            for (int nt = 0; nt < 4; ++nt) {
                ffrag z = {0.f, 0.f, 0.f, 0.f};
                acc0[nt] = __builtin_amdgcn_mfma_f32_16x16x32_bf16(aCur, w0f[nt], z, 0, 0, 0);
            }
            // prefetch next subtile's A while H round-trip is in flight
            const int stN = st + 4;
            bfrag aNxt = {0, 0, 0, 0, 0, 0, 0, 0};
            int gidNxt = 0;
            if (stN < nst) gidNxt = load_a(xs, gidb, stN * 16, l15, q, cnt, &aNxt);

            // ---- H = relu(acc0 + b0) -> LDS (C-layout -> A-layout transform) ----
            #pragma unroll
            for (int nt = 0; nt < 4; ++nt)
                #pragma unroll
                for (int r = 0; r < 4; ++r) {
                    float h = acc0[nt][r] + b0v[nt];
                    h = h > 0.f ? h : 0.f;
                    H[(q * 4 + r) * 72 + nt * 16 + l15] = bf16r(h);
                }

            // ---- layer 1: two K=32 steps over H ----
            bfrag a10 = *(const bfrag*)(H + l15 * 72 + q * 8);
            bfrag a11 = *(const bfrag*)(H + l15 * 72 + 32 + q * 8);
            ffrag acc1[4];
            #pragma unroll
            for (int nt = 0; nt < 4; ++nt) {
                ffrag z = {0.f, 0.f, 0.f, 0.f};
                acc1[nt] = __builtin_amdgcn_mfma_f32_16x16x32_bf16(a10, w1f[nt][0], z, 0, 0, 0);
                acc1[nt] = __builtin_amdgcn_mfma_f32_16x16x32_bf16(a11, w1f[nt][1], acc1[nt], 0, 0, 0);
            }

            // ---- layer 2: relu(acc1+b1) . W2, reduce over 16 n-lanes ----
            #pragma unroll
            for (int r = 0; r < 4; ++r) {
                float p = 0.f;
                #pragma unroll
                for (int nt = 0; nt < 4; ++nt) {
                    float h = acc1[nt][r] + b1v[nt];
                    h = h > 0.f ? h : 0.f;
                    p = fmaf(h, w2v[nt], p);
                }
                p += __shfl_xor(p, 1);
                p += __shfl_xor(p, 2);
                p += __shfl_xor(p, 4);
                p += __shfl_xor(p, 8);
                // lane whose l15 equals row-in-subtile (q*4+r) owns that row's gid
                if (l15 == q * 4 + r && st * 16 + l15 < cnt)
                    out[gidCur] = p + b2v;
            }

            st = stN;
            aCur = aNxt;
            gidCur = gidNxt;
        }
    }
}

// ---------- fallback: per-thread fp32 ----------
__global__ void k_fallback(const int* __restrict__ idxs, const float* __restrict__ xs,
                           const float* __restrict__ W0, const float* __restrict__ b0,
                           const float* __restrict__ W1, const float* __restrict__ b1,
                           const float* __restrict__ W2, const float* __restrict__ b2,
                           float* __restrict__ out, int N) {
    int n = blockIdx.x * blockDim.x + threadIdx.x;
    if (n >= N) return;
    int k = idxs[n];
    float h0[64];
    #pragma unroll
    for (int j = 0; j < 64; ++j) h0[j] = b0[k * 64 + j];
    for (int i = 0; i < 16; ++i) {
        float xi = xs[(size_t)n * 16 + i];
        #pragma unroll
        for (int j = 0; j < 64; ++j) h0[j] = fmaf(xi, W0[k * 1024 + i * 64 + j], h0[j]);
    }
    #pragma unroll
    for (int j = 0; j < 64; ++j) h0[j] = fmaxf(h0[j], 0.f);
    float acc = b2[k];
    for (int jc = 0; jc < 4; ++jc) {
        float h1[16];
        #pragma unroll
        for (int j = 0; j < 16; ++j) h1[j] = b1[k * 64 + jc * 16 + j];
        for (int i = 0; i < 64; ++i) {
            float hv = h0[i];
            #pragma unroll
            for (int j = 0; j < 16; ++j)
                h1[j] = fmaf(hv, W1[k * 4096 + i * 64 + jc * 16 + j], h1[j]);
        }
        #pragma unroll
        for (int j = 0; j < 16; ++j) acc = fmaf(fmaxf(h1[j], 0.f), W2[k * 64 + jc * 16 + j], acc);
    }
    out[n] = acc;
}

extern "C" void kernel_launch(void* const* d_in, const int* in_sizes, int n_in,
                              void* d_out, int out_size, void* d_ws, size_t ws_size,
                              hipStream_t stream) {
    const int*   idxs = (const int*)d_in[0];
    const float* xs   = (const float*)d_in[1];
    const float* W0   = (const float*)d_in[2];
    const float* b0   = (const float*)d_in[3];
    const float* W1   = (const float*)d_in[4];
    const float* b1   = (const float*)d_in[5];
    const float* W2   = (const float*)d_in[6];
    const float* b2   = (const float*)d_in[7];
    float* out = (float*)d_out;
    const int N = in_sizes[0];  // 1,048,576

    const size_t need = (size_t)GIDS_OFF + (size_t)N * 4;
    if (N != SPAN * NSPANS || ws_size < need) {
        k_fallback<<<(N + 255) / 256, 256, 0, stream>>>(idxs, xs, W0, b0, W1, b1, W2, b2, out, N);
        return;
    }

    unsigned char* wsB = (unsigned char*)d_ws;
    int* wsI = (int*)d_ws;
    k_build_images<<<8, 256, 0, stream>>>(W0, b0, W1, b1, W2, b2, wsB);
    k_sort<<<NSPANS, 256, 0, stream>>>(idxs, wsI);
    k_mlp<<<NSPANS, 256, 0, stream>>>(xs, wsB, out);
}

// Round 4
// 159.738 us; speedup vs baseline: 1.2040x; 1.0531x over previous
//
#include <hip/hip_runtime.h>

// MultiPropMLP on MI355X: N=1M samples, MLP 16->64->64->1, per-sample weight
// set k in [0,8) via idxs (fp32 buffers, values bf16-rounded).
// Round 4: Phase A = fused block-local sort + gather + bf16 A-fragment pack
// (streaming, BW-bound). Phase B = 1 wave per (span,k) bucket, no barriers,
// weights in registers, permuted H layout for cheap pack (v_perm) writes.

typedef __attribute__((ext_vector_type(8))) short bfrag;   // 8 bf16 (4 VGPRs)
typedef __attribute__((ext_vector_type(4))) float ffrag;   // 4 fp32 acc

#define SPAN        1024
#define NSPANS      1024
#define HDR_OFF     0                         // int[NSPANS*16]: cnt[8] | rstart[8]
#define IMG_OFF     65536
#define IMG_STRIDE  13312                     // W0B 4096 | W1B 8192 | bias 772 -> pad
#define OG_OFF      (IMG_OFF + 8 * IMG_STRIDE)        // 172032, int[NSPANS*SPAN]
#define XG_OFF      (OG_OFF + NSPANS * SPAN * 4)      // 4366336, 32 B/row
#define WS_NEED     ((size_t)XG_OFF + (size_t)NSPANS * SPAN * 32 + 512)

__device__ __forceinline__ unsigned short bf16r(float f) {
    unsigned int u = __float_as_uint(f);
    u += 0x7fffu + ((u >> 16) & 1u);
    return (unsigned short)(u >> 16);
}
// pack two fp32 (already exact bf16) -> u32 [lo=bf16(lo), hi=bf16(hi)] via v_perm
__device__ __forceinline__ unsigned int pack_trunc(float hiF, float loF) {
    return __builtin_amdgcn_perm(__float_as_uint(hiF), __float_as_uint(loF), 0x07060302u);
}
// round-half-up pack (for non-exact values): err <= 0.5 ulp except exact ties
__device__ __forceinline__ unsigned int pack_rnd(float hiF, float loF) {
    return __builtin_amdgcn_perm(__float_as_uint(hiF) + 0x8000u,
                                 __float_as_uint(loF) + 0x8000u, 0x07060302u);
}

// ---------- K0: per-k weight images ----------
// W0B @0   (4096 B): [4 nt][64 lane][8 j] bf16, B-frag for 16x16x32, k=q*8+j (0 for k>=16)
// W1B @4096(8192 B): [4 nt][2 s][64 lane][8 j] bf16, PERMUTED k-order:
//                    h = (j&3)*16 + s*8 + q*2 + (j>>2)   (matches H slot p(h)=(h&15)*4+(h>>4))
// bias @12288: f32 b0[64] | b1[64] | W2[64] | b2
__global__ void k_build_images(const float* __restrict__ W0, const float* __restrict__ b0,
                               const float* __restrict__ W1, const float* __restrict__ b1,
                               const float* __restrict__ W2, const float* __restrict__ b2,
                               unsigned char* __restrict__ wsB) {
    const int k = blockIdx.x, t = threadIdx.x;
    unsigned char* img = wsB + IMG_OFF + k * IMG_STRIDE;
    unsigned short* w0b = (unsigned short*)img;
    unsigned short* w1b = (unsigned short*)(img + 4096);
    float* bias = (float*)(img + 12288);
    for (int e = t; e < 2048; e += 256) {
        int j = e & 7, lane = (e >> 3) & 63, nt = e >> 9, q = lane >> 4;
        int kk = q * 8 + j;
        w0b[e] = (kk < 16) ? bf16r(W0[k * 1024 + kk * 64 + nt * 16 + (lane & 15)])
                           : (unsigned short)0;
    }
    for (int e = t; e < 4096; e += 256) {
        int j = e & 7, lane = (e >> 3) & 63, s = (e >> 9) & 1, nt = e >> 10, q = lane >> 4;
        int h = (j & 3) * 16 + s * 8 + q * 2 + (j >> 2);
        w1b[e] = bf16r(W1[k * 4096 + h * 64 + nt * 16 + (lane & 15)]);
    }
    if (t < 64) bias[t] = b0[k * 64 + t];
    else if (t < 128) bias[64 + (t - 64)] = b1[k * 64 + (t - 64)];
    else if (t < 192) bias[128 + (t - 128)] = W2[k * 64 + (t - 128)];
    else if (t == 192) bias[192] = b2[k];
}

// ---------- K1: fused sort + gather + pack over 1024-sample spans ----------
__global__ __launch_bounds__(256) void k_sortgather(const int* __restrict__ idxs,
                                                    const float* __restrict__ xs,
                                                    unsigned char* __restrict__ wsB) {
    __shared__ int wcnt[4][4][8];
    __shared__ int bsbase[4][4][8];
    __shared__ int cntS[8], startS[8];
    __shared__ int sId[SPAN];
    const int tid = threadIdx.x, lane = tid & 63, w = tid >> 6;
    const int base = blockIdx.x * SPAN;
    int* hdr = (int*)(wsB + HDR_OFF) + blockIdx.x * 16;

    int kreg[4], lrank[4];
    #pragma unroll
    for (int it = 0; it < 4; ++it) {
        int k = idxs[base + it * 256 + tid];
        kreg[it] = k;
        unsigned long long mymask = 0;
        #pragma unroll
        for (int kk = 0; kk < 8; ++kk) {
            unsigned long long m = __ballot(k == kk);
            if (k == kk) mymask = m;
            if (lane == 0) wcnt[it][w][kk] = (int)__popcll(m);
        }
        lrank[it] = (int)__popcll(mymask & ((1ull << lane) - 1ull));
    }
    __syncthreads();
    if (tid < 8) {
        int c = 0;
        for (int it = 0; it < 4; ++it)
            for (int w2 = 0; w2 < 4; ++w2) c += wcnt[it][w2][tid];
        cntS[tid] = c;
        hdr[tid] = c;
    }
    __syncthreads();
    if (tid == 0) {
        int s = 0;
        for (int k = 0; k < 8; ++k) { startS[k] = s; s += cntS[k]; }
    }
    __syncthreads();
    if (tid < 8) hdr[8 + tid] = startS[tid];
    if (tid < 128) {
        int it = tid >> 5, w2 = (tid >> 3) & 3, kk = tid & 7;
        int b = startS[kk];
        for (int it2 = 0; it2 < it; ++it2)
            for (int w3 = 0; w3 < 4; ++w3) b += wcnt[it2][w3][kk];
        for (int w3 = 0; w3 < w2; ++w3) b += wcnt[it][w3][kk];
        bsbase[it][w2][kk] = b;
    }
    __syncthreads();
    #pragma unroll
    for (int it = 0; it < 4; ++it)
        sId[bsbase[it][w][kreg[it]] + lrank[it]] = it * 256 + tid;
    __syncthreads();

    // gather X rows in sorted order, pack to bf16 A-frag layout (exact: trunc)
    int* ogG = (int*)(wsB + OG_OFF) + base;
    unsigned char* xg = wsB + XG_OFF + (size_t)blockIdx.x * (SPAN * 32);
    #pragma unroll
    for (int it = 0; it < 4; ++it) {
        const int R = it * 256 + tid;
        const int gid = base + sId[R];
        ogG[R] = gid;
        const float4* p = (const float4*)(xs + (size_t)gid * 16);
        float4 f0 = p[0], f1 = p[1], f2 = p[2], f3 = p[3];
        uint4 lo, hi;
        lo.x = pack_trunc(f0.y, f0.x); lo.y = pack_trunc(f0.w, f0.z);
        lo.z = pack_trunc(f1.y, f1.x); lo.w = pack_trunc(f1.w, f1.z);
        hi.x = pack_trunc(f2.y, f2.x); hi.y = pack_trunc(f2.w, f2.z);
        hi.z = pack_trunc(f3.y, f3.x); hi.w = pack_trunc(f3.w, f3.z);
        const int g = R >> 4, m = R & 15;
        *(uint4*)(xg + g * 512 + m * 16)       = lo;   // q=0 chunk (k 0..7)
        *(uint4*)(xg + g * 512 + 256 + m * 16) = hi;   // q=1 chunk (k 8..15)
    }
}

// ---------- K2: MLP, one wave per (span, k) bucket ----------
// H3 slot layout: hidden h stored at slot p(h)=(h&15)*4+(h>>4), row stride 72
// shorts (144 B). Writes: 4 x ds_write_b64 contiguous; reads: 2 x ds_read_b128.
__global__ __launch_bounds__(64, 4) void k_mlp(const unsigned char* __restrict__ wsB,
                                               float* __restrict__ out) {
    __shared__ __align__(16) unsigned short H3[16 * 72];
    const int b = blockIdx.x, span = b >> 3, k = b & 7;
    const int* hdr = (const int*)(wsB + HDR_OFF) + span * 16;
    const int cnt = hdr[k];
    if (cnt == 0) return;
    const int rstart = hdr[8 + k];
    const int* og = (const int*)(wsB + OG_OFF) + span * SPAN;
    const unsigned char* xg = wsB + XG_OFF + (size_t)span * (SPAN * 32);
    const unsigned char* img = wsB + IMG_OFF + k * IMG_STRIDE;

    const int lane = threadIdx.x & 63, q = lane >> 4, l15 = lane & 15;

    bfrag w0f[4], w1f[4][2];
    #pragma unroll
    for (int nt = 0; nt < 4; ++nt)
        w0f[nt] = *(const bfrag*)(img + nt * 1024 + lane * 16);
    #pragma unroll
    for (int nt = 0; nt < 4; ++nt)
        #pragma unroll
        for (int s = 0; s < 2; ++s)
            w1f[nt][s] = *(const bfrag*)(img + 4096 + ((nt * 2 + s) * 64 + lane) * 16);
    const float* bias = (const float*)(img + 12288);
    float b0v[4], b1v[4], w2v[4];
    #pragma unroll
    for (int nt = 0; nt < 4; ++nt) {
        b0v[nt] = bias[nt * 16 + l15];
        b1v[nt] = bias[64 + nt * 16 + l15];
        w2v[nt] = bias[128 + nt * 16 + l15];
    }
    const float b2v = bias[192];

    const int nst = (cnt + 15) >> 4;

    // subtile A loader: row R in span-sorted order; q>=2 lanes carry zeros
    auto loadA = [&](int st, bfrag* a, int* gid) {
        int R = rstart + st * 16 + l15;
        R = R < (SPAN - 1) ? R : (SPAN - 1);
        *gid = og[R];
        bfrag av = {0, 0, 0, 0, 0, 0, 0, 0};
        if (q < 2)
            av = *(const bfrag*)(xg + ((R >> 4) * 512 + q * 256 + (R & 15) * 16));
        *a = av;
    };

    bfrag aCur;
    int gidCur;
    loadA(0, &aCur, &gidCur);

    for (int st = 0; st < nst; ++st) {
        // ---- layer 0: 4 x mfma 16x16x32 (K zero-padded 16..31) ----
        ffrag acc0[4];
        #pragma unroll
        for (int nt = 0; nt < 4; ++nt) {
            ffrag z = {0.f, 0.f, 0.f, 0.f};
            acc0[nt] = __builtin_amdgcn_mfma_f32_16x16x32_bf16(aCur, w0f[nt], z, 0, 0, 0);
        }
        // prefetch next subtile
        bfrag aNxt = {0, 0, 0, 0, 0, 0, 0, 0};
        int gidNxt = 0;
        if (st + 1 < nst) loadA(st + 1, &aNxt, &gidNxt);

        // ---- H = relu(acc0 + b0) -> LDS (packed, permuted slots) ----
        #pragma unroll
        for (int r = 0; r < 4; ++r) {
            float v0 = acc0[0][r] + b0v[0]; v0 = v0 > 0.f ? v0 : 0.f;
            float v1 = acc0[1][r] + b0v[1]; v1 = v1 > 0.f ? v1 : 0.f;
            float v2 = acc0[2][r] + b0v[2]; v2 = v2 > 0.f ? v2 : 0.f;
            float v3 = acc0[3][r] + b0v[3]; v3 = v3 > 0.f ? v3 : 0.f;
            uint2 u;
            u.x = pack_rnd(v1, v0);
            u.y = pack_rnd(v3, v2);
            *(uint2*)((unsigned char*)H3 + (q * 4 + r) * 144 + l15 * 8) = u;
        }

        // ---- layer 1: 8 x mfma over permuted H slots ----
        bfrag a10 = *(const bfrag*)((unsigned char*)H3 + l15 * 144 + q * 16);
        bfrag a11 = *(const bfrag*)((unsigned char*)H3 + l15 * 144 + 64 + q * 16);
        ffrag acc1[4];
        #pragma unroll
        for (int nt = 0; nt < 4; ++nt) {
            ffrag z = {0.f, 0.f, 0.f, 0.f};
            acc1[nt] = __builtin_amdgcn_mfma_f32_16x16x32_bf16(a10, w1f[nt][0], z, 0, 0, 0);
            acc1[nt] = __builtin_amdgcn_mfma_f32_16x16x32_bf16(a11, w1f[nt][1], acc1[nt], 0, 0, 0);
        }

        // ---- layer 2: relu(acc1+b1) . W2 + b2, reduce over 16 n-lanes ----
        #pragma unroll
        for (int r = 0; r < 4; ++r) {
            float p = 0.f;
            #pragma unroll
            for (int nt = 0; nt < 4; ++nt) {
                float h = acc1[nt][r] + b1v[nt];
                h = h > 0.f ? h : 0.f;
                p = fmaf(h, w2v[nt], p);
            }
            p += __shfl_xor(p, 1);
            p += __shfl_xor(p, 2);
            p += __shfl_xor(p, 4);
            p += __shfl_xor(p, 8);
            if (l15 == q * 4 + r && st * 16 + l15 < cnt)
                out[gidCur] = p + b2v;
        }

        aCur = aNxt;
        gidCur = gidNxt;
    }
}

// ---------- fallback: per-thread fp32 ----------
__global__ void k_fallback(const int* __restrict__ idxs, const float* __restrict__ xs,
                           const float* __restrict__ W0, const float* __restrict__ b0,
                           const float* __restrict__ W1, const float* __restrict__ b1,
                           const float* __restrict__ W2, const float* __restrict__ b2,
                           float* __restrict__ out, int N) {
    int n = blockIdx.x * blockDim.x + threadIdx.x;
    if (n >= N) return;
    int k = idxs[n];
    float h0[64];
    #pragma unroll
    for (int j = 0; j < 64; ++j) h0[j] = b0[k * 64 + j];
    for (int i = 0; i < 16; ++i) {
        float xi = xs[(size_t)n * 16 + i];
        #pragma unroll
        for (int j = 0; j < 64; ++j) h0[j] = fmaf(xi, W0[k * 1024 + i * 64 + j], h0[j]);
    }
    #pragma unroll
    for (int j = 0; j < 64; ++j) h0[j] = fmaxf(h0[j], 0.f);
    float acc = b2[k];
    for (int jc = 0; jc < 4; ++jc) {
        float h1[16];
        #pragma unroll
        for (int j = 0; j < 16; ++j) h1[j] = b1[k * 64 + jc * 16 + j];
        for (int i = 0; i < 64; ++i) {
            float hv = h0[i];
            #pragma unroll
            for (int j = 0; j < 16; ++j)
                h1[j] = fmaf(hv, W1[k * 4096 + i * 64 + jc * 16 + j], h1[j]);
        }
        #pragma unroll
        for (int j = 0; j < 16; ++j) acc = fmaf(fmaxf(h1[j], 0.f), W2[k * 64 + jc * 16 + j], acc);
    }
    out[n] = acc;
}

extern "C" void kernel_launch(void* const* d_in, const int* in_sizes, int n_in,
                              void* d_out, int out_size, void* d_ws, size_t ws_size,
                              hipStream_t stream) {
    const int*   idxs = (const int*)d_in[0];
    const float* xs   = (const float*)d_in[1];
    const float* W0   = (const float*)d_in[2];
    const float* b0   = (const float*)d_in[3];
    const float* W1   = (const float*)d_in[4];
    const float* b1   = (const float*)d_in[5];
    const float* W2   = (const float*)d_in[6];
    const float* b2   = (const float*)d_in[7];
    float* out = (float*)d_out;
    const int N = in_sizes[0];  // 1,048,576

    if (N != SPAN * NSPANS || ws_size < WS_NEED) {
        k_fallback<<<(N + 255) / 256, 256, 0, stream>>>(idxs, xs, W0, b0, W1, b1, W2, b2, out, N);
        return;
    }

    unsigned char* wsB = (unsigned char*)d_ws;
    k_build_images<<<8, 256, 0, stream>>>(W0, b0, W1, b1, W2, b2, wsB);
    k_sortgather<<<NSPANS, 256, 0, stream>>>(idxs, xs, wsB);
    k_mlp<<<NSPANS * 8, 64, 0, stream>>>(wsB, out);
}

// Round 5
// 137.796 us; speedup vs baseline: 1.3957x; 1.1592x over previous
//
#include <hip/hip_runtime.h>

// MultiPropMLP on MI355X: N=1M samples, MLP 16->64->64->1, per-sample weight
// set k in [0,8) via idxs (fp32 buffers, values bf16-rounded).
// Round 5: ONE fused kernel per 512-sample span: block-local counting sort ->
// gather+bf16-pack X into LDS -> per-wave MFMA MLP (k in {w, w+4}) -> staged
// coalesced out write. No intermediate HBM traffic. Layer 2 runs as MFMA with
// a single-column B fragment (k-permuted like W1B). Weight images built once
// per launch in ws (B-fragment order, L2-hot).

typedef __attribute__((ext_vector_type(8))) short bfrag;   // 8 bf16 (4 VGPRs)
typedef __attribute__((ext_vector_type(4))) float ffrag;   // 4 fp32 acc

#define SPAN        512
#define NSPANS      2048
#define IMG_STRIDE  15360     // W0B 4096 | W1B 8192 | W2B 2048 | bias f32[129]
#define WS_NEED     ((size_t)(8 * IMG_STRIDE))

__device__ __forceinline__ unsigned short bf16r(float f) {
    unsigned int u = __float_as_uint(f);
    u += 0x7fffu + ((u >> 16) & 1u);
    return (unsigned short)(u >> 16);
}
// pack two fp32 (already exact bf16) -> u32 via byte-perm (truncation exact)
__device__ __forceinline__ unsigned int pack_trunc(float hiF, float loF) {
    return __builtin_amdgcn_perm(__float_as_uint(hiF), __float_as_uint(loF), 0x07060302u);
}
// round-half-up pack (<=0.5 ulp bf16)
__device__ __forceinline__ unsigned int pack_rnd(float hiF, float loF) {
    return __builtin_amdgcn_perm(__float_as_uint(hiF) + 0x8000u,
                                 __float_as_uint(loF) + 0x8000u, 0x07060302u);
}

// ---------- K0: per-k weight images (MFMA B-fragment order) ----------
// W0B @0    : [4 nt][64 lane][8 j] bf16, k=q*8+j (zero for k>=16)
// W1B @4096 : [4 nt][2 s][64 lane][8 j] bf16, permuted k: h=(j&3)*16+s*8+q*2+(j>>2)
// W2B @12288: [2 s][64 lane][8 j] bf16, col n=l15==0 only, same k-permutation
// bias @14336: f32 b0[64] | b1[64] | b2
__global__ void k_build_images(const float* __restrict__ W0, const float* __restrict__ b0,
                               const float* __restrict__ W1, const float* __restrict__ b1,
                               const float* __restrict__ W2, const float* __restrict__ b2,
                               unsigned char* __restrict__ wsB) {
    const int k = blockIdx.x, t = threadIdx.x;
    unsigned char* img = wsB + k * IMG_STRIDE;
    unsigned short* w0b = (unsigned short*)img;
    unsigned short* w1b = (unsigned short*)(img + 4096);
    unsigned short* w2b = (unsigned short*)(img + 12288);
    float* bias = (float*)(img + 14336);
    for (int e = t; e < 2048; e += 256) {
        int j = e & 7, lane = (e >> 3) & 63, nt = e >> 9, q = lane >> 4;
        int kk = q * 8 + j;
        w0b[e] = (kk < 16) ? bf16r(W0[k * 1024 + kk * 64 + nt * 16 + (lane & 15)])
                           : (unsigned short)0;
    }
    for (int e = t; e < 4096; e += 256) {
        int j = e & 7, lane = (e >> 3) & 63, s = (e >> 9) & 1, nt = e >> 10, q = lane >> 4;
        int h = (j & 3) * 16 + s * 8 + q * 2 + (j >> 2);
        w1b[e] = bf16r(W1[k * 4096 + h * 64 + nt * 16 + (lane & 15)]);
    }
    for (int e = t; e < 1024; e += 256) {
        int j = e & 7, lane = (e >> 3) & 63, s = e >> 9, q = lane >> 4, l15 = lane & 15;
        int h = (j & 3) * 16 + s * 8 + q * 2 + (j >> 2);
        w2b[e] = (l15 == 0) ? bf16r(W2[k * 64 + h]) : (unsigned short)0;
    }
    if (t < 64) bias[t] = b0[k * 64 + t];
    else if (t < 128) bias[t] = b1[k * 64 + (t - 64)];
    else if (t == 128) bias[128] = b2[k];
}

// ---------- K1: fused sort + gather + MFMA MLP, one 512-sample span/block ----------
__global__ __launch_bounds__(256, 4) void k_fused(const int* __restrict__ idxs,
                                                  const float* __restrict__ xs,
                                                  const unsigned char* __restrict__ wsB,
                                                  float* __restrict__ out) {
    __shared__ int wcnt[2][4][8];
    __shared__ int bsbase[2][4][8];
    __shared__ int cntS[8], startS[8];
    __shared__ unsigned short sId[SPAN];                       // 1 KB
    __shared__ __align__(16) unsigned short Xg[SPAN * 16];     // 16 KB  [g][q][m][8]
    __shared__ __align__(16) unsigned short H3[4][16 * 72];    // 9 KB per-wave
    __shared__ float outBuf[SPAN];                             // 2 KB

    const int tid = threadIdx.x, lane = tid & 63, w = tid >> 6;
    const int q = lane >> 4, l15 = lane & 15;
    const int base = blockIdx.x * SPAN;

    // ---- phase S: block-local counting sort (ballot ranks, stable) ----
    int kreg[2], lrank[2];
    #pragma unroll
    for (int it = 0; it < 2; ++it) {
        int k = idxs[base + it * 256 + tid];
        kreg[it] = k;
        unsigned long long mymask = 0;
        #pragma unroll
        for (int kk = 0; kk < 8; ++kk) {
            unsigned long long m = __ballot(k == kk);
            if (k == kk) mymask = m;
            if (lane == 0) wcnt[it][w][kk] = (int)__popcll(m);
        }
        lrank[it] = (int)__popcll(mymask & ((1ull << lane) - 1ull));
    }
    __syncthreads();
    if (tid < 8) {
        int c = 0;
        for (int it = 0; it < 2; ++it)
            for (int w2 = 0; w2 < 4; ++w2) c += wcnt[it][w2][tid];
        cntS[tid] = c;
    }
    __syncthreads();
    if (tid == 0) {
        int s = 0;
        for (int k = 0; k < 8; ++k) { startS[k] = s; s += cntS[k]; }
    }
    __syncthreads();
    if (tid < 64) {
        int it = tid >> 5, w2 = (tid >> 3) & 3, kk = tid & 7;
        int b = startS[kk];
        for (int it2 = 0; it2 < it; ++it2)
            for (int w3 = 0; w3 < 4; ++w3) b += wcnt[it2][w3][kk];
        for (int w3 = 0; w3 < w2; ++w3) b += wcnt[it][w3][kk];
        bsbase[it][w2][kk] = b;
    }
    __syncthreads();
    #pragma unroll
    for (int it = 0; it < 2; ++it)
        sId[bsbase[it][w][kreg[it]] + lrank[it]] = (unsigned short)(it * 256 + tid);
    __syncthreads();

    // ---- phase G: gather X rows in sorted order, pack bf16 A-frag layout ----
    #pragma unroll
    for (int it = 0; it < 2; ++it) {
        const int r = it * 256 + tid;
        const int gid = base + (int)sId[r];
        const float4* p = (const float4*)(xs + (size_t)gid * 16);
        float4 f0 = p[0], f1 = p[1], f2 = p[2], f3 = p[3];
        uint4 lo, hi;
        lo.x = pack_trunc(f0.y, f0.x); lo.y = pack_trunc(f0.w, f0.z);
        lo.z = pack_trunc(f1.y, f1.x); lo.w = pack_trunc(f1.w, f1.z);
        hi.x = pack_trunc(f2.y, f2.x); hi.y = pack_trunc(f2.w, f2.z);
        hi.z = pack_trunc(f3.y, f3.x); hi.w = pack_trunc(f3.w, f3.z);
        const int g = r >> 4, m = r & 15;
        *(uint4*)(Xg + g * 256 + m * 8)       = lo;   // q=0 chunk (k 0..7)
        *(uint4*)(Xg + g * 256 + 128 + m * 8) = hi;   // q=1 chunk (k 8..15)
    }
    __syncthreads();

    // ---- phase M: wave w processes buckets k = w, w+4 ----
    unsigned short* H = H3[w];
    #pragma unroll
    for (int kk2 = 0; kk2 < 2; ++kk2) {
        const int k = w + kk2 * 4;
        const int cnt = cntS[k];
        if (cnt == 0) continue;
        const int start = startS[k];
        const unsigned char* img = wsB + k * IMG_STRIDE;

        bfrag w0f[4], w1f[4][2], w2f[2];
        #pragma unroll
        for (int nt = 0; nt < 4; ++nt)
            w0f[nt] = *(const bfrag*)(img + nt * 1024 + lane * 16);
        #pragma unroll
        for (int nt = 0; nt < 4; ++nt)
            #pragma unroll
            for (int s = 0; s < 2; ++s)
                w1f[nt][s] = *(const bfrag*)(img + 4096 + ((nt * 2 + s) * 64 + lane) * 16);
        #pragma unroll
        for (int s = 0; s < 2; ++s)
            w2f[s] = *(const bfrag*)(img + 12288 + (s * 64 + lane) * 16);
        const float* bias = (const float*)(img + 14336);
        float b0v[4], b1v[4];
        #pragma unroll
        for (int nt = 0; nt < 4; ++nt) {
            b0v[nt] = bias[nt * 16 + l15];
            b1v[nt] = bias[64 + nt * 16 + l15];
        }
        const float b2v = bias[128];

        const int nst = (cnt + 15) >> 4;

        auto loadA = [&](int st) -> bfrag {
            int R = start + st * 16 + l15;
            int Rm = start + cnt - 1;
            R = R < Rm ? R : Rm;
            bfrag av = {0, 0, 0, 0, 0, 0, 0, 0};
            if (q < 2)
                av = *(const bfrag*)(Xg + (R >> 4) * 256 + q * 128 + (R & 15) * 8);
            return av;
        };

        bfrag aCur = loadA(0);
        for (int st = 0; st < nst; ++st) {
            // ---- layer 0: 4 x mfma (K zero-padded 16..31) ----
            ffrag acc0[4];
            #pragma unroll
            for (int nt = 0; nt < 4; ++nt) {
                ffrag z = {0.f, 0.f, 0.f, 0.f};
                acc0[nt] = __builtin_amdgcn_mfma_f32_16x16x32_bf16(aCur, w0f[nt], z, 0, 0, 0);
            }
            bfrag aNxt = {0, 0, 0, 0, 0, 0, 0, 0};
            if (st + 1 < nst) aNxt = loadA(st + 1);

            // ---- H1 = relu(acc0 + b0) -> LDS (permuted slots, packed) ----
            #pragma unroll
            for (int r = 0; r < 4; ++r) {
                float v0 = acc0[0][r] + b0v[0]; v0 = v0 > 0.f ? v0 : 0.f;
                float v1 = acc0[1][r] + b0v[1]; v1 = v1 > 0.f ? v1 : 0.f;
                float v2 = acc0[2][r] + b0v[2]; v2 = v2 > 0.f ? v2 : 0.f;
                float v3 = acc0[3][r] + b0v[3]; v3 = v3 > 0.f ? v3 : 0.f;
                uint2 u;
                u.x = pack_rnd(v1, v0);
                u.y = pack_rnd(v3, v2);
                *(uint2*)((unsigned char*)H + (q * 4 + r) * 144 + l15 * 8) = u;
            }

            // ---- layer 1: 8 x mfma over permuted H slots ----
            bfrag a10 = *(const bfrag*)((unsigned char*)H + l15 * 144 + q * 16);
            bfrag a11 = *(const bfrag*)((unsigned char*)H + l15 * 144 + 64 + q * 16);
            ffrag acc1[4];
            #pragma unroll
            for (int nt = 0; nt < 4; ++nt) {
                ffrag z = {0.f, 0.f, 0.f, 0.f};
                acc1[nt] = __builtin_amdgcn_mfma_f32_16x16x32_bf16(a10, w1f[nt][0], z, 0, 0, 0);
                acc1[nt] = __builtin_amdgcn_mfma_f32_16x16x32_bf16(a11, w1f[nt][1], acc1[nt], 0, 0, 0);
            }

            // ---- H2 = relu(acc1 + b1) -> same LDS slots (data-dep orders DS) ----
            #pragma unroll
            for (int r = 0; r < 4; ++r) {
                float v0 = acc1[0][r] + b1v[0]; v0 = v0 > 0.f ? v0 : 0.f;
                float v1 = acc1[1][r] + b1v[1]; v1 = v1 > 0.f ? v1 : 0.f;
                float v2 = acc1[2][r] + b1v[2]; v2 = v2 > 0.f ? v2 : 0.f;
                float v3 = acc1[3][r] + b1v[3]; v3 = v3 > 0.f ? v3 : 0.f;
                uint2 u;
                u.x = pack_rnd(v1, v0);
                u.y = pack_rnd(v3, v2);
                *(uint2*)((unsigned char*)H + (q * 4 + r) * 144 + l15 * 8) = u;
            }

            // ---- layer 2: 2 x mfma vs single-column W2B ----
            bfrag a20 = *(const bfrag*)((unsigned char*)H + l15 * 144 + q * 16);
            bfrag a21 = *(const bfrag*)((unsigned char*)H + l15 * 144 + 64 + q * 16);
            ffrag d;
            {
                ffrag z = {0.f, 0.f, 0.f, 0.f};
                d = __builtin_amdgcn_mfma_f32_16x16x32_bf16(a20, w2f[0], z, 0, 0, 0);
                d = __builtin_amdgcn_mfma_f32_16x16x32_bf16(a21, w2f[1], d, 0, 0, 0);
            }

            // ---- store: column n=0 lives in lanes l15==0, row m=q*4+r ----
            if (l15 == 0) {
                #pragma unroll
                for (int r = 0; r < 4; ++r) {
                    int row = st * 16 + q * 4 + r;
                    if (row < cnt) {
                        int oid = (int)sId[start + row];
                        outBuf[oid] = d[r] + b2v;
                    }
                }
            }

            aCur = aNxt;
        }
    }
    __syncthreads();

    // ---- phase O: coalesced out write (512 floats) ----
    ((float2*)(out + base))[tid] = ((const float2*)outBuf)[tid];
}

// ---------- fallback: per-thread fp32 ----------
__global__ void k_fallback(const int* __restrict__ idxs, const float* __restrict__ xs,
                           const float* __restrict__ W0, const float* __restrict__ b0,
                           const float* __restrict__ W1, const float* __restrict__ b1,
                           const float* __restrict__ W2, const float* __restrict__ b2,
                           float* __restrict__ out, int N) {
    int n = blockIdx.x * blockDim.x + threadIdx.x;
    if (n >= N) return;
    int k = idxs[n];
    float h0[64];
    #pragma unroll
    for (int j = 0; j < 64; ++j) h0[j] = b0[k * 64 + j];
    for (int i = 0; i < 16; ++i) {
        float xi = xs[(size_t)n * 16 + i];
        #pragma unroll
        for (int j = 0; j < 64; ++j) h0[j] = fmaf(xi, W0[k * 1024 + i * 64 + j], h0[j]);
    }
    #pragma unroll
    for (int j = 0; j < 64; ++j) h0[j] = fmaxf(h0[j], 0.f);
    float acc = b2[k];
    for (int jc = 0; jc < 4; ++jc) {
        float h1[16];
        #pragma unroll
        for (int j = 0; j < 16; ++j) h1[j] = b1[k * 64 + jc * 16 + j];
        for (int i = 0; i < 64; ++i) {
            float hv = h0[i];
            #pragma unroll
            for (int j = 0; j < 16; ++j)
                h1[j] = fmaf(hv, W1[k * 4096 + i * 64 + jc * 16 + j], h1[j]);
        }
        #pragma unroll
        for (int j = 0; j < 16; ++j) acc = fmaf(fmaxf(h1[j], 0.f), W2[k * 64 + jc * 16 + j], acc);
    }
    out[n] = acc;
}

extern "C" void kernel_launch(void* const* d_in, const int* in_sizes, int n_in,
                              void* d_out, int out_size, void* d_ws, size_t ws_size,
                              hipStream_t stream) {
    const int*   idxs = (const int*)d_in[0];
    const float* xs   = (const float*)d_in[1];
    const float* W0   = (const float*)d_in[2];
    const float* b0   = (const float*)d_in[3];
    const float* W1   = (const float*)d_in[4];
    const float* b1   = (const float*)d_in[5];
    const float* W2   = (const float*)d_in[6];
    const float* b2   = (const float*)d_in[7];
    float* out = (float*)d_out;
    const int N = in_sizes[0];  // 1,048,576

    if (N != SPAN * NSPANS || ws_size < WS_NEED) {
        k_fallback<<<(N + 255) / 256, 256, 0, stream>>>(idxs, xs, W0, b0, W1, b1, W2, b2, out, N);
        return;
    }

    unsigned char* wsB = (unsigned char*)d_ws;
    k_build_images<<<8, 256, 0, stream>>>(W0, b0, W1, b1, W2, b2, wsB);
    k_fused<<<NSPANS, 256, 0, stream>>>(idxs, xs, wsB, out);
}